// Round 6
// baseline (282.484 us; speedup 1.0000x reference)
//
#include <hip/hip_runtime.h>
#include <hip/hip_bf16.h>
#include <stdint.h>

// ---------------------------------------------------------------------------
// JointEmbeddingClassifier on MI355X (gfx950) — R9b (R9 resubmission; prior
// round died on container acquisition, not on the kernel).
// R8 post-mortem: budget = gemm1 70.5 + head 26.5 + [prep + fixed] ~151us
// (constant across R4-R8). prep's dominant cost is the x f32->bf16 cast
// (96 MB of its ~169 MB traffic), and gemm1 re-reads xb (32 MB): 128 MB
// total for a tensor that can be read ONCE as f32 (64 MB).
// R9: fuse the cast into gemm1's A-staging.
//   - A path: per chunk, 8x global_load_dwordx4 (f32, swizzled source,
//     coalesced) -> v_cvt_pk_bf16_f32 (HW RNE == previous SW RNE bits)
//     -> ds_write_b128 into the same swizzled LDS layout. LDS bytes
//     unchanged -> the LDS-BW bound that sets gemm1's time is untouched.
//   - vm ops/chunk/thread = 10 (2 B-gload_lds + 8 A-f32); end-of-chunk
//     vmcnt(10) -> all older chunks' ops done (B(c+1) in LDS, A(c+1) regs
//     ready); then cvt+write A(c+1) to slot (c+1)%3 (WAR-safe: its readers
//     finished 2 barriers ago); lgkmcnt(0) before s_barrier publishes the
//     ds_writes. Two named A-reg sets, unroll-by-2 parity (rule #20).
//   - prep drops the cast blocks (14465 -> 6273 blocks, 169 -> 73 MB).
// k_head byte-identical to R8.
// ---------------------------------------------------------------------------

typedef __attribute__((ext_vector_type(4))) float    floatx4;
typedef __attribute__((ext_vector_type(8))) short    shortx8;
typedef __attribute__((ext_vector_type(4))) short    shortx4;
typedef __attribute__((ext_vector_type(4))) uint32_t uintx4;
typedef __attribute__((ext_vector_type(8))) __bf16   bf16x8;

static __device__ __forceinline__ ushort f32_to_bf16_rne(float f) {
  uint32_t u = __builtin_bit_cast(uint32_t, f);
  u += 0x7FFFu + ((u >> 16) & 1u);      // RNE (no NaN inputs here)
  return (ushort)(u >> 16);
}

static __device__ __forceinline__ uint32_t cvt_pk_bf16(float lo, float hi) {
  uint32_t r;
  asm("v_cvt_pk_bf16_f32 %0, %1, %2" : "=v"(r) : "v"(lo), "v"(hi));
  return r;
}

// async global->LDS, 16B per lane. LDS dest = wave-uniform base + lane*16;
// global address may be fully per-lane (used for perm-indirected rows).
static __device__ __forceinline__ void async_copy16(const void* g, void* lds) {
  __builtin_amdgcn_global_load_lds(
      (__attribute__((address_space(1))) void*)(uintptr_t)g,
      (__attribute__((address_space(3))) void*)(uintptr_t)lds,
      16, 0, 0);
}

// ======================= fused prep (one launch) ===========================
// blocks [0]            : counting sort of y -> perm, offs, work-list
// blocks [1, 4224]      : pack cwb [32][128][1024] + Wcb [128][1024]
// blocks [4225, 6272]   : transpose Wp|Ws -> Bt1 bf16 [2048][4096]
__global__ __launch_bounds__(256) void k_prep(
    const int* __restrict__ y,
    const float* __restrict__ Wp,  const float* __restrict__ Ws,
    const float* __restrict__ Wc,
    const float* __restrict__ cw0, const float* __restrict__ cw1,
    ushort* __restrict__ Bt1,
    ushort* __restrict__ cwb, ushort* __restrict__ Wcb,
    int* __restrict__ perm, int* __restrict__ offs,
    int* __restrict__ work, int* __restrict__ nwork)
{
  __shared__ __align__(16) ushort tile[64 * 72];
  __shared__ int hist[32], hbase[32], hcur[32];
  const int b = blockIdx.x;
  const int t = threadIdx.x;

  if (b == 0) {
    // ---- bucket: counting sort by class (intra-class order irrelevant) ----
    if (t < 32) { hist[t] = 0; hcur[t] = 0; }
    __syncthreads();
    int yv[16];
    #pragma unroll
    for (int i = 0; i < 16; ++i) { yv[i] = y[t * 16 + i]; atomicAdd(&hist[yv[i]], 1); }
    __syncthreads();
    if (t == 0) {
      int s = 0;
      for (int c = 0; c < 32; ++c) { hbase[c] = s; offs[c] = s; s += hist[c]; }
      offs[32] = s;
      // ---- live-item work list: parent m-tiles then child (cls, mtile) ----
      int nw = 0;
      for (int m = 0; m < 32; ++m) work[nw++] = (32 << 8) | m;
      for (int c = 0; c < 32; ++c)
        for (int m0 = 0; m0 < hist[c]; m0 += 128) work[nw++] = (c << 8) | (m0 >> 7);
      nwork[0] = nw;                     // <= 96
    }
    __syncthreads();
    #pragma unroll
    for (int i = 0; i < 16; ++i) {
      const int c = yv[i];
      const int p = atomicAdd(&hcur[c], 1);
      perm[hbase[c] + p] = t * 16 + i;
    }
  } else if (b <= 4224) {
    // ---- pack cwb (rows: 32 cw0 | 64 cw1 | 32 zero per class) + Wcb ----
    const int row = b - 1;               // 0..4223
    const int k = t * 4;
    float v0 = 0.f, v1 = 0.f, v2 = 0.f, v3 = 0.f;
    ushort* dst;
    if (row < 4096) {
      const int c = row >> 7, n = row & 127;
      if (n < 32) {
        floatx4 f = *reinterpret_cast<const floatx4*>(cw0 + (size_t)(c * 32 + n) * 1024 + k);
        v0 = f[0]; v1 = f[1]; v2 = f[2]; v3 = f[3];
      } else if (n < 96) {
        floatx4 f = *reinterpret_cast<const floatx4*>(cw1 + (size_t)(c * 64 + (n - 32)) * 1024 + k);
        v0 = f[0]; v1 = f[1]; v2 = f[2]; v3 = f[3];
      }
      dst = cwb + (size_t)row * 1024 + k;
    } else {
      const int n = row - 4096;          // 0..127
      if (n < 32) {
        v0 = Wc[(k + 0) * 32 + n]; v1 = Wc[(k + 1) * 32 + n];
        v2 = Wc[(k + 2) * 32 + n]; v3 = Wc[(k + 3) * 32 + n];
      }
      dst = Wcb + (size_t)n * 1024 + k;
    }
    shortx4 o;
    o[0] = (short)f32_to_bf16_rne(v0); o[1] = (short)f32_to_bf16_rne(v1);
    o[2] = (short)f32_to_bf16_rne(v2); o[3] = (short)f32_to_bf16_rne(v3);
    *reinterpret_cast<shortx4*>(dst) = o;
  } else {
    // ---- transpose one 64x64 tile of Wp|Ws into Bt1 (K-contiguous) ----
    const int vt = b - 4225;             // 0..2047
    const int z = vt >> 10, rest = vt & 1023;
    const int nt = rest >> 6, kt = rest & 63;
    const float* W = z ? Ws : Wp;
    const int r = t >> 4, c = (t & 15) * 4;
    #pragma unroll
    for (int j = 0; j < 4; ++j) {
      const int kk = r + j * 16;
      floatx4 v = *reinterpret_cast<const floatx4*>(
          W + (size_t)(kt * 64 + kk) * 1024 + nt * 64 + c);
      tile[(c + 0) * 72 + kk] = f32_to_bf16_rne(v[0]);
      tile[(c + 1) * 72 + kk] = f32_to_bf16_rne(v[1]);
      tile[(c + 2) * 72 + kk] = f32_to_bf16_rne(v[2]);
      tile[(c + 3) * 72 + kk] = f32_to_bf16_rne(v[3]);
    }
    __syncthreads();
    const int nl = t >> 3, ch = t & 7;
    #pragma unroll
    for (int j = 0; j < 2; ++j) {
      const int n = nl + j * 32;
      shortx8 v = *reinterpret_cast<const shortx8*>(tile + n * 72 + ch * 8);
      *reinterpret_cast<shortx8*>(
          Bt1 + (size_t)(z * 1024 + nt * 64 + n) * 4096 + kt * 64 + ch * 8) = v;
    }
  }
}

// ======================= gemm1: fused x-cast A-staging =====================
// C[4096,2048] = bf16(x) . Bt1^T. 256x128 tile, 8 waves (4M x 2N), BK=64,
// ring-3. A: reg-staged f32 -> cvt_pk_bf16 -> ds_write (swizzled layout);
// B: global_load_lds from Bt1 (pre-swizzled source). 10 vm ops/chunk/thread.
__global__ __launch_bounds__(512, 2) void k_gemm1(
    const float* __restrict__ x, const ushort* __restrict__ Bt1,
    const float* __restrict__ bp, const float* __restrict__ bs,
    float* __restrict__ outP, float* __restrict__ outS,
    ushort* __restrict__ Pb, ushort* __restrict__ Sb)
{
  __shared__ __align__(16) ushort lA[3 * 256 * 64];   // 96 KB, 3 ring slots
  __shared__ __align__(16) ushort lB[3 * 128 * 64];   // 48 KB, 3 ring slots

  floatx4 acc[4][4];
  const floatx4 z4 = {0.f, 0.f, 0.f, 0.f};
  #pragma unroll
  for (int i = 0; i < 4; ++i)
    #pragma unroll
    for (int j = 0; j < 4; ++j) acc[i][j] = z4;

  const int t    = threadIdx.x;
  const int w    = t >> 6;
  const int lane = t & 63;
  const int wr   = w >> 1;      // 0..3 : M wave
  const int wc   = w & 1;       // 0..1 : N wave
  const int r16  = lane & 15;
  const int qd   = lane >> 4;

  const float*  Ax    = x   + (size_t)(blockIdx.x * 256) * 4096;
  const ushort* Bbase = Bt1 + (size_t)(blockIdx.y * 128) * 4096;

  // staging per-thread constants: per call, thread t covers row = j*64+(t>>3),
  // physical 16B chunk p = t&7; source logical chunk q = p ^ (row&7) (row&7
  // == rS&7 since j*64 is a multiple of 8).
  const int rS   = t >> 3;                    // 0..63 row-in-call
  const int pA   = t & 7;                     // dest physical chunk
  const int q    = pA ^ (rS & 7);             // source logical chunk
  const int qf   = q << 3;                    // f32 elem offset (A source)
  const int qsB  = q << 3;                    // ushort elem offset (B source)
  const int dUni = (t & ~63) * 8;             // wave-uniform B dest (ushorts)

  // per-thread A source row pointers (4 row groups)
  const float* aSrc0 = Ax + (size_t)(0 * 64 + rS) * 4096 + qf;
  const float* aSrc1 = Ax + (size_t)(1 * 64 + rS) * 4096 + qf;
  const float* aSrc2 = Ax + (size_t)(2 * 64 + rS) * 4096 + qf;
  const float* aSrc3 = Ax + (size_t)(3 * 64 + rS) * 4096 + qf;

  // ds-read per-thread bases (ushort units)
  const int px0 = (0 * 4 + qd) ^ (r16 & 7);
  const int px1 = (1 * 4 + qd) ^ (r16 & 7);
  const int aRd = (wr * 64 + r16) * 64;
  const int bRd = (wc * 64 + r16) * 64;

  floatx4 aEv[8], aOd[8];                     // two named A reg sets

  #define STAGE_B(slot, k0)                                                  \
    do {                                                                     \
      async_copy16(Bbase + (size_t)(0 * 64 + rS) * 4096 + (k0) + qsB,        \
                   lB + (slot) * 8192 + 0 * 4096 + dUni);                    \
      async_copy16(Bbase + (size_t)(1 * 64 + rS) * 4096 + (k0) + qsB,        \
                   lB + (slot) * 8192 + 1 * 4096 + dUni);                    \
    } while (0)

  #define LOAD_A(reg, k0)                                                    \
    do {                                                                     \
      reg[0] = *reinterpret_cast<const floatx4*>(aSrc0 + (k0));              \
      reg[1] = *reinterpret_cast<const floatx4*>(aSrc0 + (k0) + 4);          \
      reg[2] = *reinterpret_cast<const floatx4*>(aSrc1 + (k0));              \
      reg[3] = *reinterpret_cast<const floatx4*>(aSrc1 + (k0) + 4);          \
      reg[4] = *reinterpret_cast<const floatx4*>(aSrc2 + (k0));              \
      reg[5] = *reinterpret_cast<const floatx4*>(aSrc2 + (k0) + 4);          \
      reg[6] = *reinterpret_cast<const floatx4*>(aSrc3 + (k0));              \
      reg[7] = *reinterpret_cast<const floatx4*>(aSrc3 + (k0) + 4);          \
    } while (0)

  #define WRITE_A(reg, slot)                                                 \
    do {                                                                     \
      _Pragma("unroll")                                                      \
      for (int j = 0; j < 4; ++j) {                                          \
        uintx4 o;                                                            \
        o[0] = cvt_pk_bf16(reg[2*j][0],   reg[2*j][1]);                      \
        o[1] = cvt_pk_bf16(reg[2*j][2],   reg[2*j][3]);                      \
        o[2] = cvt_pk_bf16(reg[2*j+1][0], reg[2*j+1][1]);                    \
        o[3] = cvt_pk_bf16(reg[2*j+1][2], reg[2*j+1][3]);                    \
        *reinterpret_cast<uintx4*>(                                          \
            lA + (slot) * 16384 + (j * 64 + rS) * 64 + pA * 8) = o;          \
      }                                                                      \
    } while (0)

  // ---- prologue: chunks 0,1 issued (20 vm ops); A(0) written to slot 0 ----
  STAGE_B(0, 0);   LOAD_A(aEv, 0);
  STAGE_B(1, 64);  LOAD_A(aOd, 64);
  asm volatile("s_waitcnt vmcnt(10)" ::: "memory");   // chunk 0's 10 done
  WRITE_A(aEv, 0);
  asm volatile("s_waitcnt lgkmcnt(0)" ::: "memory");
  __builtin_amdgcn_s_barrier();
  asm volatile("" ::: "memory");

  #define CHUNK_BODY(c, regIssue, regWrite)                                  \
    do {                                                                     \
      const int slot = (c) % 3;                                              \
      const ushort* As = lA + slot * 16384;                                  \
      const ushort* Bs = lB + slot * 8192;                                   \
      bf16x8 af[2][4], bfv[2][4];                                            \
      _Pragma("unroll")                                                      \
      for (int mi = 0; mi < 4; ++mi) {                                       \
        af[0][mi] = *reinterpret_cast<const bf16x8*>(As + aRd + mi * 1024 + px0 * 8); \
        af[1][mi] = *reinterpret_cast<const bf16x8*>(As + aRd + mi * 1024 + px1 * 8); \
      }                                                                      \
      _Pragma("unroll")                                                      \
      for (int ni = 0; ni < 4; ++ni) {                                       \
        bfv[0][ni] = *reinterpret_cast<const bf16x8*>(Bs + bRd + ni * 1024 + px0 * 8); \
        bfv[1][ni] = *reinterpret_cast<const bf16x8*>(Bs + bRd + ni * 1024 + px1 * 8); \
      }                                                                      \
      const int cs  = (c) + 2;                                               \
      const int ss  = cs % 3;                                                \
      const int k0s = (cs < 64 ? cs : 63) * 64;                              \
      STAGE_B(ss, k0s);                                                      \
      LOAD_A(regIssue, k0s);                                                 \
      __builtin_amdgcn_s_setprio(1);                                         \
      _Pragma("unroll")                                                      \
      for (int ks = 0; ks < 2; ++ks)                                         \
        _Pragma("unroll")                                                    \
        for (int mi = 0; mi < 4; ++mi)                                       \
          _Pragma("unroll")                                                  \
          for (int ni = 0; ni < 4; ++ni)                                     \
            acc[mi][ni] = __builtin_amdgcn_mfma_f32_16x16x32_bf16(           \
                af[ks][mi], bfv[ks][ni], acc[mi][ni], 0, 0, 0);              \
      __builtin_amdgcn_s_setprio(0);                                         \
      asm volatile("s_waitcnt vmcnt(10)" ::: "memory");                      \
      WRITE_A(regWrite, ((c) + 1) % 3);                                      \
      asm volatile("s_waitcnt lgkmcnt(0)" ::: "memory");                     \
      __builtin_amdgcn_s_barrier();                                          \
      asm volatile("" ::: "memory");                                         \
    } while (0)

  for (int c = 0; c < 64; c += 2) {
    CHUNK_BODY(c,     aEv, aOd);   // even: issue A(c+2)->aEv, write A(c+1) from aOd
    CHUNK_BODY(c + 1, aOd, aEv);   // odd : issue A(c+3)->aOd, write A(c+2) from aEv
  }
  #undef CHUNK_BODY
  #undef STAGE_B
  #undef LOAD_A
  #undef WRITE_A

  const int sel = (blockIdx.y >= 8);
  const float* bias = sel ? bs : bp;
  float*  outF = sel ? outS : outP;
  ushort* outB = sel ? Sb : Pb;
  const int colbase = blockIdx.y * 128 - sel * 1024;
  #pragma unroll
  for (int mi = 0; mi < 4; ++mi) {
    #pragma unroll
    for (int ni = 0; ni < 4; ++ni) {
      const int n = colbase + wc * 64 + ni * 16 + r16;
      const float bv = bias[n];
      #pragma unroll
      for (int rg = 0; rg < 4; ++rg) {
        const int m = blockIdx.x * 256 + wr * 64 + mi * 16 + qd * 4 + rg;
        const float v = acc[mi][ni][rg] + bv;
        const size_t off = (size_t)m * 1024 + n;
        outF[off] = v;
        outB[off] = f32_to_bf16_rne(v);
      }
    }
  }
}

// ======================= head: work-list, ring-4 depth-3 ===================
static __device__ __forceinline__ void load_frags64(
    const ushort* lA, const ushort* lB, bf16x8 af[2][4], bf16x8 bfv[2][4],
    int wr, int wc, int r16, int quad)
{
  #pragma unroll
  for (int ks = 0; ks < 2; ++ks) {
    const int pc = (((ks * 4) + quad) ^ (r16 & 7)) * 8;
    #pragma unroll
    for (int mi = 0; mi < 4; ++mi)
      af[ks][mi] = *reinterpret_cast<const bf16x8*>(lA + (wr * 64 + mi * 16 + r16) * 64 + pc);
    #pragma unroll
    for (int ni = 0; ni < 4; ++ni)
      bfv[ks][ni] = *reinterpret_cast<const bf16x8*>(lB + (wc * 64 + ni * 16 + r16) * 64 + pc);
  }
}

static __device__ __forceinline__ void mfma_frags64(
    bf16x8 af[2][4], bf16x8 bfv[2][4], floatx4 acc[4][4])
{
  __builtin_amdgcn_s_setprio(1);
  #pragma unroll
  for (int ks = 0; ks < 2; ++ks)
    #pragma unroll
    for (int mi = 0; mi < 4; ++mi)
      #pragma unroll
      for (int ni = 0; ni < 4; ++ni)
        acc[mi][ni] = __builtin_amdgcn_mfma_f32_16x16x32_bf16(
            af[ks][mi], bfv[ks][ni], acc[mi][ni], 0, 0, 0);
  __builtin_amdgcn_s_setprio(0);
}

// 96 blocks grid-stride the live-item list. item = (cls<<8)|mtile;
// cls==32 -> parent logits m-tile; cls<32 -> child logits for class cls.
__global__ __launch_bounds__(256) void k_head(
    const ushort* __restrict__ Sb, const ushort* __restrict__ Pb,
    const ushort* __restrict__ cwb, const ushort* __restrict__ Wcb,
    const int* __restrict__ perm, const int* __restrict__ off,
    const int* __restrict__ work, const int* __restrict__ nwork,
    const float* __restrict__ cb0, const float* __restrict__ cb1,
    const float* __restrict__ bc,
    float* __restrict__ out0, float* __restrict__ out1,
    float* __restrict__ outParent)
{
  __shared__ __align__(16) ushort lA[4 * 128 * 64];   // 64 KB, 4 ring slots
  __shared__ __align__(16) ushort lB[4 * 128 * 64];   // 64 KB, 4 ring slots

  const int t = threadIdx.x, w = t >> 6, lane = t & 63;
  const int wr = w >> 1, wc = w & 1, r16 = lane & 15, quad = lane >> 4;
  const int sr = lane >> 3, sc = lane & 7;
  const int gc = sc ^ sr;                 // source 16B-chunk (swizzled)
  const int dRow = 32 * w;                // wave's base row per staging call
  const int nW = nwork[0];

  for (int wi = blockIdx.x; wi < nW; wi += 96) {
    const int item = work[wi];
    const int cls  = item >> 8;           // 0..32
    const int mt   = item & 255;          // m-tile index

    floatx4 acc[4][4];
    const floatx4 z4 = {0.f, 0.f, 0.f, 0.f};
    #pragma unroll
    for (int i = 0; i < 4; ++i)
      #pragma unroll
      for (int j = 0; j < 4; ++j) acc[i][j] = z4;

    // per-item A/B addressing
    int off0 = 0, cnt = 0;
    const ushort* Asrc;
    const ushort* Bb;
    int rowG[4];
    if (cls == 32) {                      // parent: A = Pb rows, B = Wcb
      Asrc = Pb;
      Bb   = Wcb;
      #pragma unroll
      for (int c2 = 0; c2 < 4; ++c2) rowG[c2] = mt * 128 + dRow + 8 * c2 + sr;
    } else {                              // child: A = Sb rows via perm
      off0 = off[cls];
      cnt  = off[cls + 1] - off0;
      Asrc = Sb;
      Bb   = cwb + (size_t)cls * 128 * 1024;
      #pragma unroll
      for (int c2 = 0; c2 < 4; ++c2) {
        const int r = mt * 128 + dRow + 8 * c2 + sr;
        rowG[c2] = perm[off0 + min(r, cnt - 1)];
      }
    }

    #define STAGE_H(slot, k0)                                                  \
      do {                                                                     \
        _Pragma("unroll")                                                      \
        for (int c2 = 0; c2 < 4; ++c2) {                                       \
          async_copy16(Asrc + (size_t)rowG[c2] * 1024 + (k0) + gc * 8,         \
                       lA + (slot) * 8192 + (dRow + 8 * c2) * 64);             \
          async_copy16(Bb + (size_t)(dRow + 8 * c2 + sr) * 1024 + (k0) + gc * 8,\
                       lB + (slot) * 8192 + (dRow + 8 * c2) * 64);             \
        }                                                                      \
      } while (0)

    // prologue: stage chunks 0,1,2 (24 loads); vmcnt(16) -> chunk 0's 8 done
    // (also drains any clamped leftovers from the previous item: <=16 old +
    //  24 new - 16 kept = old fully complete + new chunk 0).
    STAGE_H(0, 0);
    STAGE_H(1, 64);
    STAGE_H(2, 128);
    asm volatile("s_waitcnt vmcnt(16)" ::: "memory");
    __builtin_amdgcn_s_barrier();
    asm volatile("" ::: "memory");

    for (int c = 0; c < 16; ++c) {
      const int slot = c & 3;
      bf16x8 af[2][4], bfv[2][4];
      load_frags64(lA + slot * 8192, lB + slot * 8192, af, bfv, wr, wc, r16, quad);
      {
        const int cs  = c + 3;            // depth-3 prefetch
        const int ss  = cs & 3;
        const int k0s = (cs < 16 ? cs : 15) * 64;
        STAGE_H(ss, k0s);
      }
      mfma_frags64(af, bfv, acc);
      // <=16 outstanding leaves chunks {c+2,c+3} in flight -> c+1 resident.
      asm volatile("s_waitcnt vmcnt(16)" ::: "memory");
      __builtin_amdgcn_s_barrier();
      asm volatile("" ::: "memory");
    }
    #undef STAGE_H

    // epilogue
    if (cls == 32) {
      if (wc == 0) {
        #pragma unroll
        for (int mi = 0; mi < 4; ++mi)
          #pragma unroll
          for (int ni = 0; ni < 2; ++ni) {
            const int n = ni * 16 + r16;
            const float bv = bc[n];
            #pragma unroll
            for (int rg = 0; rg < 4; ++rg) {
              const int m = mt * 128 + wr * 64 + mi * 16 + quad * 4 + rg;
              outParent[(size_t)m * 32 + n] = acc[mi][ni][rg] + bv;
            }
          }
      }
    } else {
      const int m0 = mt * 128;
      #pragma unroll
      for (int mi = 0; mi < 4; ++mi) {
        #pragma unroll
        for (int rg = 0; rg < 4; ++rg) {
          const int gm = m0 + wr * 64 + mi * 16 + quad * 4 + rg;
          if (gm >= cnt) continue;
          const int sample = perm[off0 + gm];
          #pragma unroll
          for (int ni = 0; ni < 4; ++ni) {
            const int n = wc * 64 + ni * 16 + r16;
            if (n < 32)
              out0[(size_t)sample * 32 + n] = acc[mi][ni][rg] + cb0[cls * 32 + n];
            else if (n < 96)
              out1[(size_t)sample * 64 + (n - 32)] = acc[mi][ni][rg] + cb1[cls * 64 + (n - 32)];
          }
        }
      }
    }
  }
}

// ---------------------------------------------------------------------------

extern "C" void kernel_launch(void* const* d_in, const int* in_sizes, int n_in,
                              void* d_out, int out_size, void* d_ws, size_t ws_size,
                              hipStream_t stream) {
  const float* x   = (const float*)d_in[0];
  const int*   y   = (const int*)  d_in[1];
  const float* Wp  = (const float*)d_in[2];
  const float* bp  = (const float*)d_in[3];
  const float* Ws  = (const float*)d_in[4];
  const float* bs  = (const float*)d_in[5];
  const float* Wc  = (const float*)d_in[6];
  const float* bc  = (const float*)d_in[7];
  const float* cw0 = (const float*)d_in[8];
  const float* cb0 = (const float*)d_in[9];
  const float* cw1 = (const float*)d_in[10];
  const float* cb1 = (const float*)d_in[11];

  float* out = (float*)d_out;
  float* parent_logits = out;               // [4096,32]
  float* child0        = out + 131072;      // [4096,32]
  float* child1        = out + 262144;      // [4096,64]
  float* P             = out + 524288;      // [4096,1024]
  float* S             = out + 4718592;     // [4096,1024]

  char* ws = (char*)d_ws;
  ushort* Bt1  = (ushort*)(ws + 33554432);       // 16 MB   [2048][4096]
  ushort* Pb   = (ushort*)(ws + 50331648);       // 8 MB    [4096][1024]
  ushort* Sb   = (ushort*)(ws + 58720256);       // 8 MB    [4096][1024]
  ushort* cwb  = (ushort*)(ws + 67108864);       // 8 MB    [32][128][1024]
  ushort* Wcb  = (ushort*)(ws + 75497472);       // 256 KB  [128][1024]
  int*    perm = (int*)   (ws + 75759616);       // 16 KB
  int*    offs = (int*)   (ws + 75776000);       // 132 B
  int*    work = (int*)   (ws + 75776256);       // 512 B  (<=96 items)
  int*    nwk  = (int*)   (ws + 75776768);       // 4 B

  k_prep <<<6273, 256, 0, stream>>>(y, Wp, Ws, Wc, cw0, cw1,
                                    Bt1, cwb, Wcb, perm, offs, work, nwk);
  k_gemm1<<<dim3(16, 16), 512, 0, stream>>>(x, Bt1, bp, bs, P, S, Pb, Sb);
  k_head <<<96, 256, 0, stream>>>(Sb, Pb, cwb, Wcb, perm, offs, work, nwk,
                                  cb0, cb1, bc,
                                  child0, child1, parent_logits);
}

// Round 7
// 257.839 us; speedup vs baseline: 1.0956x; 1.0956x over previous
//
#include <hip/hip_runtime.h>
#include <hip/hip_bf16.h>
#include <stdint.h>

// ---------------------------------------------------------------------------
// JointEmbeddingClassifier on MI355X (gfx950) — R10.
// R9 post-mortem: fused x-cast in gemm1 inflated STAGED bytes (A f32 re-read
// per y-panel: 768MB -> 1.25GB through L2/L3 at the measured ~11TB/s fabric
// rate) -> gemm1 70.5 -> 127us. Model fits observed exactly. gemm1 is
// staged-bytes-bound; any BMxBN at 256 blocks gives ~750MB staged -> ~70us
// is this decomposition's floor. REVERTED gemm1/head/workspace to R8.
// R10's single variable: prep block consolidation (14465 -> 3601 blocks,
// same traffic, 4-8x work per block) to test the dispatch-overhead
// hypothesis for the ~151us (prep+fixed) budget block:
//   cast 8192->2048 blocks (4 iters), cwb 4224->528 (8 rows),
//   transpose 2048->1024 (2 tiles + barrier between).
// ---------------------------------------------------------------------------

typedef __attribute__((ext_vector_type(4))) float  floatx4;
typedef __attribute__((ext_vector_type(8))) short  shortx8;
typedef __attribute__((ext_vector_type(4))) short  shortx4;
typedef __attribute__((ext_vector_type(8))) __bf16 bf16x8;

static __device__ __forceinline__ ushort f32_to_bf16_rne(float f) {
  uint32_t u = __builtin_bit_cast(uint32_t, f);
  u += 0x7FFFu + ((u >> 16) & 1u);      // RNE (no NaN inputs here)
  return (ushort)(u >> 16);
}

// async global->LDS, 16B per lane. LDS dest = wave-uniform base + lane*16;
// global address may be fully per-lane (used for perm-indirected rows).
static __device__ __forceinline__ void async_copy16(const void* g, void* lds) {
  __builtin_amdgcn_global_load_lds(
      (__attribute__((address_space(1))) void*)(uintptr_t)g,
      (__attribute__((address_space(3))) void*)(uintptr_t)lds,
      16, 0, 0);
}

// ======================= fused prep (one launch, fat blocks) ===============
// block  [0]          : counting sort of y -> perm, offs, work-list
// blocks [1, 528]     : pack cwb [32][128][1024] + Wcb [128][1024] (8 rows/blk)
// blocks [529, 1552]  : transpose Wp|Ws -> Bt1 bf16 (2 64x64 tiles/blk)
// blocks [1553, 3600] : cast x f32 -> bf16 (32 KB f32 per blk)
__global__ __launch_bounds__(256) void k_prep(
    const float* __restrict__ x,   const int* __restrict__ y,
    const float* __restrict__ Wp,  const float* __restrict__ Ws,
    const float* __restrict__ Wc,
    const float* __restrict__ cw0, const float* __restrict__ cw1,
    ushort* __restrict__ xb,  ushort* __restrict__ Bt1,
    ushort* __restrict__ cwb, ushort* __restrict__ Wcb,
    int* __restrict__ perm, int* __restrict__ offs,
    int* __restrict__ work, int* __restrict__ nwork)
{
  __shared__ __align__(16) ushort tile[64 * 72];
  __shared__ int hist[32], hbase[32], hcur[32];
  const int b = blockIdx.x;
  const int t = threadIdx.x;

  if (b == 0) {
    // ---- bucket: counting sort by class (intra-class order irrelevant) ----
    if (t < 32) { hist[t] = 0; hcur[t] = 0; }
    __syncthreads();
    int yv[16];
    #pragma unroll
    for (int i = 0; i < 16; ++i) { yv[i] = y[t * 16 + i]; atomicAdd(&hist[yv[i]], 1); }
    __syncthreads();
    if (t == 0) {
      int s = 0;
      for (int c = 0; c < 32; ++c) { hbase[c] = s; offs[c] = s; s += hist[c]; }
      offs[32] = s;
      // ---- live-item work list: parent m-tiles then child (cls, mtile) ----
      int nw = 0;
      for (int m = 0; m < 32; ++m) work[nw++] = (32 << 8) | m;
      for (int c = 0; c < 32; ++c)
        for (int m0 = 0; m0 < hist[c]; m0 += 128) work[nw++] = (c << 8) | (m0 >> 7);
      nwork[0] = nw;                     // <= 96
    }
    __syncthreads();
    #pragma unroll
    for (int i = 0; i < 16; ++i) {
      const int c = yv[i];
      const int p = atomicAdd(&hcur[c], 1);
      perm[hbase[c] + p] = t * 16 + i;
    }
  } else if (b <= 528) {
    // ---- pack cwb (rows: 32 cw0 | 64 cw1 | 32 zero per class) + Wcb ----
    const int row0 = (b - 1) * 8;        // 8 rows per block, rows 0..4223
    const int k = t * 4;
    #pragma unroll
    for (int r = 0; r < 8; ++r) {
      const int row = row0 + r;
      float v0 = 0.f, v1 = 0.f, v2 = 0.f, v3 = 0.f;
      ushort* dst;
      if (row < 4096) {
        const int c = row >> 7, n = row & 127;
        if (n < 32) {
          floatx4 f = *reinterpret_cast<const floatx4*>(cw0 + (size_t)(c * 32 + n) * 1024 + k);
          v0 = f[0]; v1 = f[1]; v2 = f[2]; v3 = f[3];
        } else if (n < 96) {
          floatx4 f = *reinterpret_cast<const floatx4*>(cw1 + (size_t)(c * 64 + (n - 32)) * 1024 + k);
          v0 = f[0]; v1 = f[1]; v2 = f[2]; v3 = f[3];
        }
        dst = cwb + (size_t)row * 1024 + k;
      } else {
        const int n = row - 4096;        // 0..127
        if (n < 32) {
          v0 = Wc[(k + 0) * 32 + n]; v1 = Wc[(k + 1) * 32 + n];
          v2 = Wc[(k + 2) * 32 + n]; v3 = Wc[(k + 3) * 32 + n];
        }
        dst = Wcb + (size_t)n * 1024 + k;
      }
      shortx4 o;
      o[0] = (short)f32_to_bf16_rne(v0); o[1] = (short)f32_to_bf16_rne(v1);
      o[2] = (short)f32_to_bf16_rne(v2); o[3] = (short)f32_to_bf16_rne(v3);
      *reinterpret_cast<shortx4*>(dst) = o;
    }
  } else if (b <= 1552) {
    // ---- transpose two 64x64 tiles of Wp|Ws into Bt1 (K-contiguous) ----
    const int vt0 = (b - 529) * 2;       // 0..2046
    for (int j2 = 0; j2 < 2; ++j2) {
      const int vt = vt0 + j2;
      const int z = vt >> 10, rest = vt & 1023;
      const int nt = rest >> 6, kt = rest & 63;
      const float* W = z ? Ws : Wp;
      const int r = t >> 4, c = (t & 15) * 4;
      #pragma unroll
      for (int j = 0; j < 4; ++j) {
        const int kk = r + j * 16;
        floatx4 v = *reinterpret_cast<const floatx4*>(
            W + (size_t)(kt * 64 + kk) * 1024 + nt * 64 + c);
        tile[(c + 0) * 72 + kk] = f32_to_bf16_rne(v[0]);
        tile[(c + 1) * 72 + kk] = f32_to_bf16_rne(v[1]);
        tile[(c + 2) * 72 + kk] = f32_to_bf16_rne(v[2]);
        tile[(c + 3) * 72 + kk] = f32_to_bf16_rne(v[3]);
      }
      __syncthreads();
      const int nl = t >> 3, ch = t & 7;
      #pragma unroll
      for (int j = 0; j < 2; ++j) {
        const int n = nl + j * 32;
        shortx8 v = *reinterpret_cast<const shortx8*>(tile + n * 72 + ch * 8);
        *reinterpret_cast<shortx8*>(
            Bt1 + (size_t)(z * 1024 + nt * 64 + n) * 4096 + kt * 64 + ch * 8) = v;
      }
      __syncthreads();                   // tile[] reuse across j2
    }
  } else {
    // ---- cast x -> bf16 (4 x 2048 elems per block) ----
    const size_t base = (size_t)(b - 1553) * 8192;
    #pragma unroll
    for (int it = 0; it < 4; ++it) {
      const size_t i = base + (size_t)it * 2048 + (size_t)t * 8;
      floatx4 a = *reinterpret_cast<const floatx4*>(x + i);
      floatx4 c = *reinterpret_cast<const floatx4*>(x + i + 4);
      shortx8 o;
      o[0] = (short)f32_to_bf16_rne(a[0]); o[1] = (short)f32_to_bf16_rne(a[1]);
      o[2] = (short)f32_to_bf16_rne(a[2]); o[3] = (short)f32_to_bf16_rne(a[3]);
      o[4] = (short)f32_to_bf16_rne(c[0]); o[5] = (short)f32_to_bf16_rne(c[1]);
      o[6] = (short)f32_to_bf16_rne(c[2]); o[7] = (short)f32_to_bf16_rne(c[3]);
      *reinterpret_cast<shortx8*>(xb + i) = o;
    }
  }
}

// ======================= gemm1: 256x128, ring-3 BK=64 counted-vmcnt ========
// (exact R6/R8 version — proven 70.5us, 0 conflicts)
__global__ __launch_bounds__(512, 2) void k_gemm1(
    const ushort* __restrict__ xb, const ushort* __restrict__ Bt1,
    const float* __restrict__ bp, const float* __restrict__ bs,
    float* __restrict__ outP, float* __restrict__ outS,
    ushort* __restrict__ Pb, ushort* __restrict__ Sb)
{
  __shared__ __align__(16) ushort lA[3 * 256 * 64];   // 96 KB, 3 ring slots
  __shared__ __align__(16) ushort lB[3 * 128 * 64];   // 48 KB, 3 ring slots

  floatx4 acc[4][4];
  const floatx4 z4 = {0.f, 0.f, 0.f, 0.f};
  #pragma unroll
  for (int i = 0; i < 4; ++i)
    #pragma unroll
    for (int j = 0; j < 4; ++j) acc[i][j] = z4;

  const int t    = threadIdx.x;
  const int w    = t >> 6;
  const int lane = t & 63;
  const int wr   = w >> 1;      // 0..3 : M wave
  const int wc   = w & 1;       // 0..1 : N wave
  const int r16  = lane & 15;
  const int qd   = lane >> 4;

  const ushort* Abase = xb  + (size_t)(blockIdx.x * 256) * 4096;
  const ushort* Bbase = Bt1 + (size_t)(blockIdx.y * 128) * 4096;

  const int    rS   = t >> 3;                               // 0..63 row-in-call
  const int    qs   = ((t & 7) ^ (rS & 7)) << 3;            // elem offset
  const int    dUni = (t & ~63) * 8;   // wave-uniform dest base (ushorts)

  const int px0 = (0 * 4 + qd) ^ (r16 & 7);
  const int px1 = (1 * 4 + qd) ^ (r16 & 7);
  const int aRd = (wr * 64 + r16) * 64;
  const int bRd = (wc * 64 + r16) * 64;

  #define STAGE_CHUNK(slot, k0)                                                \
    do {                                                                       \
      _Pragma("unroll")                                                        \
      for (int j = 0; j < 4; ++j)                                              \
        async_copy16(Abase + (size_t)(j * 64 + rS) * 4096 + (k0) + qs,         \
                     lA + (slot) * 16384 + j * 4096 + dUni);                   \
      _Pragma("unroll")                                                        \
      for (int j = 0; j < 2; ++j)                                              \
        async_copy16(Bbase + (size_t)(j * 64 + rS) * 4096 + (k0) + qs,         \
                     lB + (slot) * 8192 + j * 4096 + dUni);                    \
    } while (0)

  STAGE_CHUNK(0, 0);
  STAGE_CHUNK(1, 64);
  asm volatile("s_waitcnt vmcnt(6)" ::: "memory");   // chunk 0's 6 done
  __builtin_amdgcn_s_barrier();
  asm volatile("" ::: "memory");

  for (int c = 0; c < 64; ++c) {
    const int slot = c % 3;
    const ushort* As = lA + slot * 16384;
    const ushort* Bs = lB + slot * 8192;

    bf16x8 af[2][4], bfv[2][4];
    #pragma unroll
    for (int mi = 0; mi < 4; ++mi) {
      af[0][mi] = *reinterpret_cast<const bf16x8*>(As + aRd + mi * 1024 + px0 * 8);
      af[1][mi] = *reinterpret_cast<const bf16x8*>(As + aRd + mi * 1024 + px1 * 8);
    }
    #pragma unroll
    for (int ni = 0; ni < 4; ++ni) {
      bfv[0][ni] = *reinterpret_cast<const bf16x8*>(Bs + bRd + ni * 1024 + px0 * 8);
      bfv[1][ni] = *reinterpret_cast<const bf16x8*>(Bs + bRd + ni * 1024 + px1 * 8);
    }

    {
      const int cs  = c + 2;
      const int ss  = cs % 3;
      const int k0s = (cs < 64 ? cs : 63) * 64;
      STAGE_CHUNK(ss, k0s);
    }

    __builtin_amdgcn_s_setprio(1);
    #pragma unroll
    for (int ks = 0; ks < 2; ++ks)
      #pragma unroll
      for (int mi = 0; mi < 4; ++mi)
        #pragma unroll
        for (int ni = 0; ni < 4; ++ni)
          acc[mi][ni] = __builtin_amdgcn_mfma_f32_16x16x32_bf16(
              af[ks][mi], bfv[ks][ni], acc[mi][ni], 0, 0, 0);
    __builtin_amdgcn_s_setprio(0);

    asm volatile("s_waitcnt vmcnt(6)" ::: "memory");
    __builtin_amdgcn_s_barrier();
    asm volatile("" ::: "memory");
  }
  #undef STAGE_CHUNK

  const int sel = (blockIdx.y >= 8);
  const float* bias = sel ? bs : bp;
  float*  outF = sel ? outS : outP;
  ushort* outB = sel ? Sb : Pb;
  const int colbase = blockIdx.y * 128 - sel * 1024;
  #pragma unroll
  for (int mi = 0; mi < 4; ++mi) {
    #pragma unroll
    for (int ni = 0; ni < 4; ++ni) {
      const int n = colbase + wc * 64 + ni * 16 + r16;
      const float bv = bias[n];
      #pragma unroll
      for (int rg = 0; rg < 4; ++rg) {
        const int m = blockIdx.x * 256 + wr * 64 + mi * 16 + qd * 4 + rg;
        const float v = acc[mi][ni][rg] + bv;
        const size_t off = (size_t)m * 1024 + n;
        outF[off] = v;
        outB[off] = f32_to_bf16_rne(v);
      }
    }
  }
}

// ======================= head: work-list, ring-4 depth-3 (R8 exact) ========
static __device__ __forceinline__ void load_frags64(
    const ushort* lA, const ushort* lB, bf16x8 af[2][4], bf16x8 bfv[2][4],
    int wr, int wc, int r16, int quad)
{
  #pragma unroll
  for (int ks = 0; ks < 2; ++ks) {
    const int pc = (((ks * 4) + quad) ^ (r16 & 7)) * 8;
    #pragma unroll
    for (int mi = 0; mi < 4; ++mi)
      af[ks][mi] = *reinterpret_cast<const bf16x8*>(lA + (wr * 64 + mi * 16 + r16) * 64 + pc);
    #pragma unroll
    for (int ni = 0; ni < 4; ++ni)
      bfv[ks][ni] = *reinterpret_cast<const bf16x8*>(lB + (wc * 64 + ni * 16 + r16) * 64 + pc);
  }
}

static __device__ __forceinline__ void mfma_frags64(
    bf16x8 af[2][4], bf16x8 bfv[2][4], floatx4 acc[4][4])
{
  __builtin_amdgcn_s_setprio(1);
  #pragma unroll
  for (int ks = 0; ks < 2; ++ks)
    #pragma unroll
    for (int mi = 0; mi < 4; ++mi)
      #pragma unroll
      for (int ni = 0; ni < 4; ++ni)
        acc[mi][ni] = __builtin_amdgcn_mfma_f32_16x16x32_bf16(
            af[ks][mi], bfv[ks][ni], acc[mi][ni], 0, 0, 0);
  __builtin_amdgcn_s_setprio(0);
}

// 96 blocks grid-stride the live-item list. item = (cls<<8)|mtile;
// cls==32 -> parent logits m-tile; cls<32 -> child logits for class cls.
__global__ __launch_bounds__(256) void k_head(
    const ushort* __restrict__ Sb, const ushort* __restrict__ Pb,
    const ushort* __restrict__ cwb, const ushort* __restrict__ Wcb,
    const int* __restrict__ perm, const int* __restrict__ off,
    const int* __restrict__ work, const int* __restrict__ nwork,
    const float* __restrict__ cb0, const float* __restrict__ cb1,
    const float* __restrict__ bc,
    float* __restrict__ out0, float* __restrict__ out1,
    float* __restrict__ outParent)
{
  __shared__ __align__(16) ushort lA[4 * 128 * 64];   // 64 KB, 4 ring slots
  __shared__ __align__(16) ushort lB[4 * 128 * 64];   // 64 KB, 4 ring slots

  const int t = threadIdx.x, w = t >> 6, lane = t & 63;
  const int wr = w >> 1, wc = w & 1, r16 = lane & 15, quad = lane >> 4;
  const int sr = lane >> 3, sc = lane & 7;
  const int gc = sc ^ sr;                 // source 16B-chunk (swizzled)
  const int dRow = 32 * w;                // wave's base row per staging call
  const int nW = nwork[0];

  for (int wi = blockIdx.x; wi < nW; wi += 96) {
    const int item = work[wi];
    const int cls  = item >> 8;           // 0..32
    const int mt   = item & 255;          // m-tile index

    floatx4 acc[4][4];
    const floatx4 z4 = {0.f, 0.f, 0.f, 0.f};
    #pragma unroll
    for (int i = 0; i < 4; ++i)
      #pragma unroll
      for (int j = 0; j < 4; ++j) acc[i][j] = z4;

    // per-item A/B addressing
    int off0 = 0, cnt = 0;
    const ushort* Asrc;
    const ushort* Bb;
    int rowG[4];
    if (cls == 32) {                      // parent: A = Pb rows, B = Wcb
      Asrc = Pb;
      Bb   = Wcb;
      #pragma unroll
      for (int c2 = 0; c2 < 4; ++c2) rowG[c2] = mt * 128 + dRow + 8 * c2 + sr;
    } else {                              // child: A = Sb rows via perm
      off0 = off[cls];
      cnt  = off[cls + 1] - off0;
      Asrc = Sb;
      Bb   = cwb + (size_t)cls * 128 * 1024;
      #pragma unroll
      for (int c2 = 0; c2 < 4; ++c2) {
        const int r = mt * 128 + dRow + 8 * c2 + sr;
        rowG[c2] = perm[off0 + min(r, cnt - 1)];
      }
    }

    #define STAGE_H(slot, k0)                                                  \
      do {                                                                     \
        _Pragma("unroll")                                                      \
        for (int c2 = 0; c2 < 4; ++c2) {                                       \
          async_copy16(Asrc + (size_t)rowG[c2] * 1024 + (k0) + gc * 8,         \
                       lA + (slot) * 8192 + (dRow + 8 * c2) * 64);             \
          async_copy16(Bb + (size_t)(dRow + 8 * c2 + sr) * 1024 + (k0) + gc * 8,\
                       lB + (slot) * 8192 + (dRow + 8 * c2) * 64);             \
        }                                                                      \
      } while (0)

    // prologue: stage chunks 0,1,2 (24 loads); vmcnt(16) -> chunk 0's 8 done
    // (also drains any clamped leftovers from the previous item: <=16 old +
    //  24 new - 16 kept = old fully complete + new chunk 0).
    STAGE_H(0, 0);
    STAGE_H(1, 64);
    STAGE_H(2, 128);
    asm volatile("s_waitcnt vmcnt(16)" ::: "memory");
    __builtin_amdgcn_s_barrier();
    asm volatile("" ::: "memory");

    for (int c = 0; c < 16; ++c) {
      const int slot = c & 3;
      bf16x8 af[2][4], bfv[2][4];
      load_frags64(lA + slot * 8192, lB + slot * 8192, af, bfv, wr, wc, r16, quad);
      {
        const int cs  = c + 3;            // depth-3 prefetch
        const int ss  = cs & 3;
        const int k0s = (cs < 16 ? cs : 15) * 64;
        STAGE_H(ss, k0s);
      }
      mfma_frags64(af, bfv, acc);
      // <=16 outstanding leaves chunks {c+2,c+3} in flight -> c+1 resident.
      asm volatile("s_waitcnt vmcnt(16)" ::: "memory");
      __builtin_amdgcn_s_barrier();
      asm volatile("" ::: "memory");
    }
    #undef STAGE_H

    // epilogue
    if (cls == 32) {
      if (wc == 0) {
        #pragma unroll
        for (int mi = 0; mi < 4; ++mi)
          #pragma unroll
          for (int ni = 0; ni < 2; ++ni) {
            const int n = ni * 16 + r16;
            const float bv = bc[n];
            #pragma unroll
            for (int rg = 0; rg < 4; ++rg) {
              const int m = mt * 128 + wr * 64 + mi * 16 + quad * 4 + rg;
              outParent[(size_t)m * 32 + n] = acc[mi][ni][rg] + bv;
            }
          }
      }
    } else {
      const int m0 = mt * 128;
      #pragma unroll
      for (int mi = 0; mi < 4; ++mi) {
        #pragma unroll
        for (int rg = 0; rg < 4; ++rg) {
          const int gm = m0 + wr * 64 + mi * 16 + quad * 4 + rg;
          if (gm >= cnt) continue;
          const int sample = perm[off0 + gm];
          #pragma unroll
          for (int ni = 0; ni < 4; ++ni) {
            const int n = wc * 64 + ni * 16 + r16;
            if (n < 32)
              out0[(size_t)sample * 32 + n] = acc[mi][ni][rg] + cb0[cls * 32 + n];
            else if (n < 96)
              out1[(size_t)sample * 64 + (n - 32)] = acc[mi][ni][rg] + cb1[cls * 64 + (n - 32)];
          }
        }
      }
    }
  }
}

// ---------------------------------------------------------------------------

extern "C" void kernel_launch(void* const* d_in, const int* in_sizes, int n_in,
                              void* d_out, int out_size, void* d_ws, size_t ws_size,
                              hipStream_t stream) {
  const float* x   = (const float*)d_in[0];
  const int*   y   = (const int*)  d_in[1];
  const float* Wp  = (const float*)d_in[2];
  const float* bp  = (const float*)d_in[3];
  const float* Ws  = (const float*)d_in[4];
  const float* bs  = (const float*)d_in[5];
  const float* Wc  = (const float*)d_in[6];
  const float* bc  = (const float*)d_in[7];
  const float* cw0 = (const float*)d_in[8];
  const float* cb0 = (const float*)d_in[9];
  const float* cw1 = (const float*)d_in[10];
  const float* cb1 = (const float*)d_in[11];

  float* out = (float*)d_out;
  float* parent_logits = out;               // [4096,32]
  float* child0        = out + 131072;      // [4096,32]
  float* child1        = out + 262144;      // [4096,64]
  float* P             = out + 524288;      // [4096,1024]
  float* S             = out + 4718592;     // [4096,1024]

  char* ws = (char*)d_ws;
  ushort* xb   = (ushort*)(ws);                  // 32 MB   [4096][4096]
  ushort* Bt1  = (ushort*)(ws + 33554432);       // 16 MB   [2048][4096]
  ushort* Pb   = (ushort*)(ws + 50331648);       // 8 MB    [4096][1024]
  ushort* Sb   = (ushort*)(ws + 58720256);       // 8 MB    [4096][1024]
  ushort* cwb  = (ushort*)(ws + 67108864);       // 8 MB    [32][128][1024]
  ushort* Wcb  = (ushort*)(ws + 75497472);       // 256 KB  [128][1024]
  int*    perm = (int*)   (ws + 75759616);       // 16 KB
  int*    offs = (int*)   (ws + 75776000);       // 132 B
  int*    work = (int*)   (ws + 75776256);       // 512 B  (<=96 items)
  int*    nwk  = (int*)   (ws + 75776768);       // 4 B

  k_prep <<<3601, 256, 0, stream>>>(x, y, Wp, Ws, Wc, cw0, cw1,
                                    xb, Bt1, cwb, Wcb, perm, offs, work, nwk);
  k_gemm1<<<dim3(16, 16), 512, 0, stream>>>(xb, Bt1, bp, bs, P, S, Pb, Sb);
  k_head <<<96, 256, 0, stream>>>(Sb, Pb, cwb, Wcb, perm, offs, work, nwk,
                                  cb0, cb1, bc,
                                  child0, child1, parent_logits);
}